// Round 1
// baseline (1220.060 us; speedup 1.0000x reference)
//
#include <hip/hip_runtime.h>

#define N_POINTS 100000
#define N_PAIRS  50000
#define K_OFFSETS 27
#define C 128
#define WPAD 136  // 128 + 8 bf16 pad -> LDS row stride 272B = 68 words; quarter-wave b128 reads tile all 32 banks 2-way (free)

typedef __attribute__((ext_vector_type(8))) short short8;
typedef __attribute__((ext_vector_type(4))) float floatx4;

__device__ inline unsigned short f2bf(float f) {
  unsigned int u = __float_as_uint(f);
  unsigned int r = (u + 0x7FFFu + ((u >> 16) & 1u)) >> 16;  // RNE
  return (unsigned short)r;
}

// WbT[k][d][c] = bf16(W[k][c][d])  for both layers' weights
__global__ __launch_bounds__(256) void prep_w_kernel(
    const float* __restrict__ W0, const float* __restrict__ W1,
    unsigned short* __restrict__ WT0, unsigned short* __restrict__ WT1) {
  int i = blockIdx.x * 256 + threadIdx.x;
  const int per = K_OFFSETS * C * C;
  if (i >= 2 * per) return;
  int which = i / per;
  int r = i % per;
  int k = r / (C * C);
  int q = r % (C * C);
  int d = q / C;
  int c = q % C;
  const float* W = which ? W1 : W0;
  unsigned short* WT = which ? WT1 : WT0;
  WT[k * C * C + d * C + c] = f2bf(W[k * C * C + c * C + d]);
}

// xb = bf16(features); out = broadcast(b0)
__global__ __launch_bounds__(256) void prep_x_kernel(
    const float* __restrict__ features, const float* __restrict__ b0,
    unsigned short* __restrict__ xb, float* __restrict__ out) {
  int i = (blockIdx.x * 256 + threadIdx.x) * 4;
  if (i >= N_POINTS * C) return;
  float4 f = *(const float4*)&features[i];
  ushort4 u;
  u.x = f2bf(f.x); u.y = f2bf(f.y); u.z = f2bf(f.z); u.w = f2bf(f.w);
  *(ushort4*)&xb[i] = u;
  float4 b = *(const float4*)&b0[i & 127];
  *(float4*)&out[i] = b;
}

// x1b = bf16(relu(out)); out = b1 + features   (residual fused into layer-2 init)
__global__ __launch_bounds__(256) void mid_kernel(
    const float* __restrict__ features, const float* __restrict__ b1,
    float* __restrict__ out, unsigned short* __restrict__ x1b) {
  int i = (blockIdx.x * 256 + threadIdx.x) * 4;
  if (i >= N_POINTS * C) return;
  float4 y = *(const float4*)&out[i];
  ushort4 u;
  u.x = f2bf(fmaxf(y.x, 0.f));
  u.y = f2bf(fmaxf(y.y, 0.f));
  u.z = f2bf(fmaxf(y.z, 0.f));
  u.w = f2bf(fmaxf(y.w, 0.f));
  *(ushort4*)&x1b[i] = u;
  float4 f = *(const float4*)&features[i];
  float4 b = *(const float4*)&b1[i & 127];
  float4 o;
  o.x = f.x + b.x; o.y = f.y + b.y; o.z = f.z + b.z; o.w = f.w + b.w;
  *(float4*)&out[i] = o;
}

// One (k, 64-pair tile) per block. A gathered from global (bf16 rows),
// B = W[k]^T staged in padded LDS, D scatter-atomicAdd'ed into out (fp32).
__global__ __launch_bounds__(256, 4) void conv_kernel(
    const unsigned short* __restrict__ xb, const unsigned short* __restrict__ wbt,
    const int* __restrict__ in_map, const int* __restrict__ out_map,
    float* __restrict__ out) {
  __shared__ unsigned short Wlds[C * WPAD];

  const int k = blockIdx.y;
  const int pairBase = blockIdx.x * 64;
  const int tid = threadIdx.x;

  // stage W[k]^T (128x128 bf16 = 32KB) into LDS, row stride WPAD
  const unsigned short* wk = wbt + k * C * C;
#pragma unroll
  for (int it = 0; it < 8; ++it) {
    int t = tid + it * 256;      // 2048 chunks of 8 bf16
    int row = t >> 4;
    int col = (t & 15) << 3;
    *(uint4*)&Wlds[row * WPAD + col] = *(const uint4*)&wk[row * C + col];
  }
  __syncthreads();

  const int wave = tid >> 6;
  const int lane = tid & 63;
  const int l15 = lane & 15;
  const int kg = lane >> 4;            // quad group 0..3
  const int pair0 = pairBase + wave * 16;

  // A-operand: row m = lane&15, k-chunk = (lane>>4)*8 .. +7 (contiguous 16B in the point row)
  const int prA = pair0 + l15;
  const bool validA = prA < N_PAIRS;
  const int inIdx = validA ? in_map[k * N_PAIRS + prA] : 0;
  const unsigned short* arow = xb + inIdx * C + kg * 8;

  floatx4 acc[8];
#pragma unroll
  for (int nt = 0; nt < 8; ++nt) acc[nt] = (floatx4){0.f, 0.f, 0.f, 0.f};

#pragma unroll
  for (int kk = 0; kk < 4; ++kk) {                  // K = 128 in steps of 32
    short8 a = *(const short8*)(arow + kk * 32);
    const unsigned short* bbase = &Wlds[l15 * WPAD + kk * 32 + kg * 8];
#pragma unroll
    for (int nt = 0; nt < 8; ++nt) {                // 8 n-tiles of 16 cols
      short8 b = *(const short8*)(bbase + nt * 16 * WPAD);
      acc[nt] = __builtin_amdgcn_mfma_f32_16x16x32_bf16(a, b, acc[nt], 0, 0, 0);
    }
  }

  // D layout: col = lane&15 (+16*nt), row = kg*4 + i  -> scatter-add
#pragma unroll
  for (int i = 0; i < 4; ++i) {
    int pr = pair0 + kg * 4 + i;
    if (pr < N_PAIRS) {
      int oi = out_map[k * N_PAIRS + pr];
      float* orow = out + oi * C + l15;
#pragma unroll
      for (int nt = 0; nt < 8; ++nt) {
        atomicAdd(orow + nt * 16, acc[nt][i]);
      }
    }
  }
}

extern "C" void kernel_launch(void* const* d_in, const int* in_sizes, int n_in,
                              void* d_out, int out_size, void* d_ws, size_t ws_size,
                              hipStream_t stream) {
  const float* features = (const float*)d_in[0];
  const int* in_map     = (const int*)d_in[1];
  const int* out_map    = (const int*)d_in[2];
  const float* W0       = (const float*)d_in[3];
  const float* b0       = (const float*)d_in[4];
  const float* W1       = (const float*)d_in[5];
  const float* b1       = (const float*)d_in[6];
  float* out = (float*)d_out;

  char* ws = (char*)d_ws;
  unsigned short* xb  = (unsigned short*)ws;                      // 25,600,000 B
  unsigned short* x1b = (unsigned short*)(ws + 25600000);         // 25,600,000 B
  unsigned short* WT0 = (unsigned short*)(ws + 51200000);         // 884,736 B
  unsigned short* WT1 = (unsigned short*)(ws + 52084736);         // 884,736 B

  prep_w_kernel<<<(2 * K_OFFSETS * C * C + 255) / 256, 256, 0, stream>>>(W0, W1, WT0, WT1);
  prep_x_kernel<<<(N_POINTS * C / 4 + 255) / 256, 256, 0, stream>>>(features, b0, xb, out);

  dim3 grid((N_PAIRS + 63) / 64, K_OFFSETS);
  conv_kernel<<<grid, 256, 0, stream>>>(xb, WT0, in_map, out_map, out);
  mid_kernel<<<(N_POINTS * C / 4 + 255) / 256, 256, 0, stream>>>(features, b1, out, x1b);
  conv_kernel<<<grid, 256, 0, stream>>>(x1b, WT1, in_map, out_map, out);
}

// Round 4
// 1016.148 us; speedup vs baseline: 1.2007x; 1.2007x over previous
//
#include <hip/hip_runtime.h>

#define N_POINTS 100000
#define N_PAIRS  50000
#define K_OFFSETS 27
#define C 128
#define WPAD 136   // 128 + 8 bf16 pad; LDS row stride 272B
#define CAP 48     // CSR bucket capacity; Poisson(13.5), P(>=48) ~ 3e-12 per point

typedef __attribute__((ext_vector_type(8))) short short8;
typedef __attribute__((ext_vector_type(4))) float floatx4;

__device__ inline unsigned short f2bf(float f) {
  unsigned int u = __float_as_uint(f);
  return (unsigned short)((u + 0x7FFFu + ((u >> 16) & 1u)) >> 16);  // RNE
}
__device__ inline float bf2f(unsigned int lo16) {
  return __uint_as_float(lo16 << 16);
}

// WT[k][d*C + c] = bf16(W[k][c][d])  -- natural order for BOTH layers
__global__ __launch_bounds__(256) void prep_w_kernel(
    const float* __restrict__ W0, const float* __restrict__ W1,
    unsigned short* __restrict__ WT0, unsigned short* __restrict__ WT1) {
  int i = blockIdx.x * 256 + threadIdx.x;
  const int per = K_OFFSETS * C * C;
  if (i >= 2 * per) return;
  const float* W = (i < per) ? W0 : W1;
  unsigned short* WT = (i < per) ? WT0 : WT1;
  int r = (i < per) ? i : i - per;
  int k = r / (C * C);
  int q = r % (C * C);
  int d = q / C;
  int c = q % C;
  WT[k * C * C + d * C + c] = f2bf(W[k * C * C + c * C + d]);
}

// xb = bf16(features); out = broadcast(b0) only on the fallback path
__global__ __launch_bounds__(256) void prep_x_kernel(
    const float* __restrict__ features, const float* __restrict__ b0,
    unsigned short* __restrict__ xb, float* __restrict__ out, int write_out) {
  int i = (blockIdx.x * 256 + threadIdx.x) * 4;
  if (i >= N_POINTS * C) return;
  float4 f = *(const float4*)&features[i];
  ushort4 u;
  u.x = f2bf(f.x); u.y = f2bf(f.y); u.z = f2bf(f.z); u.w = f2bf(f.w);
  *(ushort4*)&xb[i] = u;
  if (write_out) {
    float4 b = *(const float4*)&b0[i & 127];
    *(float4*)&out[i] = b;
  }
}

__global__ __launch_bounds__(256) void zero_counts_kernel(int* __restrict__ counts) {
  int i = blockIdx.x * 256 + threadIdx.x;
  if (i < N_POINTS) counts[i] = 0;
}

// bucketed CSR of out_map: entry = (k<<16) | p  (p < 50000 < 2^16)
__global__ __launch_bounds__(256) void build_csr_kernel(
    const int* __restrict__ out_map, int* __restrict__ counts, int* __restrict__ idxbuf) {
  int flat = blockIdx.x * 256 + threadIdx.x;
  if (flat >= K_OFFSETS * N_PAIRS) return;
  int o = out_map[flat];
  int k = flat / N_PAIRS;
  int p = flat - k * N_PAIRS;
  int pos = atomicAdd(&counts[o], 1);
  if (pos < CAP) idxbuf[o * CAP + pos] = (k << 16) | p;
}

// Phase A: msg[(k-k0)*P + p][slot j] = bf16((x[in_map[k,p]] @ W[k])[chan(j)])
// chan(j) = (j&7)*16 + (j>>3); slot order comes free from the MFMA D regs.
__global__ __launch_bounds__(256, 4) void conv_msg_kernel(
    const unsigned short* __restrict__ xb, const unsigned short* __restrict__ wbt,
    const int* __restrict__ in_map, unsigned short* __restrict__ msg, int k0) {
  __shared__ unsigned short Wlds[C * WPAD];

  const int k = k0 + blockIdx.y;
  const int pairBase = blockIdx.x * 64;
  const int tid = threadIdx.x;

  const unsigned short* wk = wbt + k * C * C;
#pragma unroll
  for (int it = 0; it < 8; ++it) {
    int t = tid + it * 256;
    int row = t >> 4;
    int col = (t & 15) << 3;
    *(uint4*)&Wlds[row * WPAD + col] = *(const uint4*)&wk[row * C + col];
  }
  __syncthreads();

  const int wave = tid >> 6;
  const int lane = tid & 63;
  const int l15 = lane & 15;
  const int kg = lane >> 4;
  const int pair0 = pairBase + wave * 16;

  const int prA = pair0 + l15;
  const int inIdx = (prA < N_PAIRS) ? in_map[k * N_PAIRS + prA] : 0;
  const unsigned short* arow = xb + (size_t)inIdx * C + kg * 8;

  floatx4 acc[8];
#pragma unroll
  for (int nt = 0; nt < 8; ++nt) acc[nt] = (floatx4){0.f, 0.f, 0.f, 0.f};

#pragma unroll
  for (int kk = 0; kk < 4; ++kk) {
    short8 a = *(const short8*)(arow + kk * 32);
    const unsigned short* bbase = &Wlds[l15 * WPAD + kk * 32 + kg * 8];
#pragma unroll
    for (int nt = 0; nt < 8; ++nt) {
      short8 b = *(const short8*)(bbase + nt * 16 * WPAD);
      acc[nt] = __builtin_amdgcn_mfma_f32_16x16x32_bf16(a, b, acc[nt], 0, 0, 0);
    }
  }

  // store slot j = l15*8 + nt -> lane's 8 values contiguous (uint4, coalesced)
#pragma unroll
  for (int i = 0; i < 4; ++i) {
    int pr = pair0 + kg * 4 + i;
    if (pr < N_PAIRS) {
      unsigned short* row = msg + (size_t)(blockIdx.y * N_PAIRS + pr) * C;
      uint4 v;
      v.x = (unsigned int)f2bf(acc[0][i]) | ((unsigned int)f2bf(acc[1][i]) << 16);
      v.y = (unsigned int)f2bf(acc[2][i]) | ((unsigned int)f2bf(acc[3][i]) << 16);
      v.z = (unsigned int)f2bf(acc[4][i]) | ((unsigned int)f2bf(acc[5][i]) << 16);
      v.w = (unsigned int)f2bf(acc[6][i]) | ((unsigned int)f2bf(acc[7][i]) << 16);
      *(uint4*)(row + l15 * 8) = v;
    }
  }
}

// Phase B: one wave per output point; lane owns channels c0, c0+16 (slots 2*lane, 2*lane+1).
// init_mode: 0 = resume from out, 1 = bias (layer1 first), 2 = bias + residual (layer2 first)
// fin_mode:  0 = write out (fp32), 1 = relu -> x1b (bf16, layer1 last)
__global__ __launch_bounds__(256) void gather_kernel(
    const unsigned short* __restrict__ msg, const int* __restrict__ counts,
    const int* __restrict__ idxbuf, const float* __restrict__ bias,
    const float* __restrict__ features, float* __restrict__ out,
    unsigned short* __restrict__ x1b,
    int k0, int G, int init_mode, int fin_mode) {
  const int wave = threadIdx.x >> 6;
  const int lane = threadIdx.x & 63;
  const int oi = blockIdx.x * 4 + wave;
  if (oi >= N_POINTS) return;

  const int c0 = ((2 * lane) & 7) * 16 + (lane >> 2);
  const int c1 = c0 + 16;
  const size_t base = (size_t)oi * C;

  float a0, a1;
  if (init_mode == 1)      { a0 = bias[c0]; a1 = bias[c1]; }
  else if (init_mode == 2) { a0 = bias[c0] + features[base + c0];
                             a1 = bias[c1] + features[base + c1]; }
  else                     { a0 = out[base + c0]; a1 = out[base + c1]; }

  int cnt = counts[oi]; if (cnt > CAP) cnt = CAP;
  const int* lst = idxbuf + oi * CAP;

  for (int t = 0; t < cnt; ++t) {
    int e = lst[t];                                   // wave-uniform scalar load
    unsigned int rel = (unsigned int)(e >> 16) - (unsigned int)k0;
    if (rel < (unsigned int)G) {                      // wave-uniform branch
      int p = e & 0xffff;
      unsigned int v = *(const unsigned int*)(msg + ((size_t)rel * N_PAIRS + p) * C + 2 * lane);
      a0 += bf2f(v & 0xffffu);
      a1 += bf2f(v >> 16);
    }
  }

  if (fin_mode == 1) {
    x1b[base + c0] = f2bf(fmaxf(a0, 0.f));
    x1b[base + c1] = f2bf(fmaxf(a1, 0.f));
  } else {
    out[base + c0] = a0;
    out[base + c1] = a1;
  }
}

// ---------------- fallback (round-1 atomic path, <53 MB ws, natural WT1) ----------------
__global__ __launch_bounds__(256) void mid_kernel(
    const float* __restrict__ features, const float* __restrict__ b1,
    float* __restrict__ out, unsigned short* __restrict__ x1b) {
  int i = (blockIdx.x * 256 + threadIdx.x) * 4;
  if (i >= N_POINTS * C) return;
  float4 y = *(const float4*)&out[i];
  ushort4 u;
  u.x = f2bf(fmaxf(y.x, 0.f));
  u.y = f2bf(fmaxf(y.y, 0.f));
  u.z = f2bf(fmaxf(y.z, 0.f));
  u.w = f2bf(fmaxf(y.w, 0.f));
  *(ushort4*)&x1b[i] = u;
  float4 f = *(const float4*)&features[i];
  float4 b = *(const float4*)&b1[i & 127];
  float4 o;
  o.x = f.x + b.x; o.y = f.y + b.y; o.z = f.z + b.z; o.w = f.w + b.w;
  *(float4*)&out[i] = o;
}

__global__ __launch_bounds__(256, 4) void conv_atomic_kernel(
    const unsigned short* __restrict__ xb, const unsigned short* __restrict__ wbt,
    const int* __restrict__ in_map, const int* __restrict__ out_map,
    float* __restrict__ out) {
  __shared__ unsigned short Wlds[C * WPAD];
  const int k = blockIdx.y;
  const int pairBase = blockIdx.x * 64;
  const int tid = threadIdx.x;
  const unsigned short* wk = wbt + k * C * C;
#pragma unroll
  for (int it = 0; it < 8; ++it) {
    int t = tid + it * 256;
    int row = t >> 4;
    int col = (t & 15) << 3;
    *(uint4*)&Wlds[row * WPAD + col] = *(const uint4*)&wk[row * C + col];
  }
  __syncthreads();
  const int wave = tid >> 6;
  const int lane = tid & 63;
  const int l15 = lane & 15;
  const int kg = lane >> 4;
  const int pair0 = pairBase + wave * 16;
  const int prA = pair0 + l15;
  const int inIdx = (prA < N_PAIRS) ? in_map[k * N_PAIRS + prA] : 0;
  const unsigned short* arow = xb + (size_t)inIdx * C + kg * 8;
  floatx4 acc[8];
#pragma unroll
  for (int nt = 0; nt < 8; ++nt) acc[nt] = (floatx4){0.f, 0.f, 0.f, 0.f};
#pragma unroll
  for (int kk = 0; kk < 4; ++kk) {
    short8 a = *(const short8*)(arow + kk * 32);
    const unsigned short* bbase = &Wlds[l15 * WPAD + kk * 32 + kg * 8];
#pragma unroll
    for (int nt = 0; nt < 8; ++nt) {
      short8 b = *(const short8*)(bbase + nt * 16 * WPAD);
      acc[nt] = __builtin_amdgcn_mfma_f32_16x16x32_bf16(a, b, acc[nt], 0, 0, 0);
    }
  }
#pragma unroll
  for (int i = 0; i < 4; ++i) {
    int pr = pair0 + kg * 4 + i;
    if (pr < N_PAIRS) {
      int oi = out_map[k * N_PAIRS + pr];
      float* orow = out + (size_t)oi * C + l15;
#pragma unroll
      for (int nt = 0; nt < 8; ++nt) atomicAdd(orow + nt * 16, acc[nt][i]);
    }
  }
}

extern "C" void kernel_launch(void* const* d_in, const int* in_sizes, int n_in,
                              void* d_out, int out_size, void* d_ws, size_t ws_size,
                              hipStream_t stream) {
  const float* features = (const float*)d_in[0];
  const int* in_map     = (const int*)d_in[1];
  const int* out_map    = (const int*)d_in[2];
  const float* W0       = (const float*)d_in[3];
  const float* b0       = (const float*)d_in[4];
  const float* W1       = (const float*)d_in[5];
  const float* b1       = (const float*)d_in[6];
  float* out = (float*)d_out;

  char* ws = (char*)d_ws;
  unsigned short* xb  = (unsigned short*)(ws);                  // 25,600,000
  unsigned short* x1b = (unsigned short*)(ws + 25600000);       // 25,600,000
  unsigned short* WT0 = (unsigned short*)(ws + 51200000);       //    884,736
  unsigned short* WT1 = (unsigned short*)(ws + 52084736);       //    884,736
  int* counts         = (int*)(ws + 52969472);                  //    400,384
  int* idxbuf         = (int*)(ws + 53369856);                  // 19,200,000 (100000*CAP*4)
  unsigned short* msg = (unsigned short*)(ws + 72569856);       // G * 12,800,000

  const long long MSG_K_BYTES = (long long)N_PAIRS * C * 2;     // 12.8 MB per offset
  long long avail = (long long)ws_size - 72569856LL;
  int G = 0;
  if (avail >= MSG_K_BYTES) {
    long long g = avail / MSG_K_BYTES;
    G = (int)(g > K_OFFSETS ? K_OFFSETS : g);
  }

  prep_w_kernel<<<(2 * K_OFFSETS * C * C + 255) / 256, 256, 0, stream>>>(W0, W1, WT0, WT1);
  prep_x_kernel<<<(N_POINTS * C / 4 + 255) / 256, 256, 0, stream>>>(
      features, b0, xb, out, (G > 0) ? 0 : 1);

  if (G > 0) {
    zero_counts_kernel<<<(N_POINTS + 255) / 256, 256, 0, stream>>>(counts);
    build_csr_kernel<<<(K_OFFSETS * N_PAIRS + 255) / 256, 256, 0, stream>>>(out_map, counts, idxbuf);

    const int nchunks = (K_OFFSETS + G - 1) / G;
    for (int layer = 0; layer < 2; ++layer) {
      const unsigned short* xin = layer ? x1b : xb;
      const unsigned short* wt  = layer ? WT1 : WT0;
      const float* bias         = layer ? b1  : b0;
      for (int c = 0; c < nchunks; ++c) {
        int k0 = c * G;
        int Gc = K_OFFSETS - k0 < G ? K_OFFSETS - k0 : G;
        dim3 cgrid((N_PAIRS + 63) / 64, Gc);
        conv_msg_kernel<<<cgrid, 256, 0, stream>>>(xin, wt, in_map, msg, k0);
        int init_mode = (c == 0) ? (layer ? 2 : 1) : 0;
        int fin_mode  = (layer == 0 && c == nchunks - 1) ? 1 : 0;
        gather_kernel<<<(N_POINTS + 3) / 4, 256, 0, stream>>>(
            msg, counts, idxbuf, bias, features, out, x1b, k0, Gc, init_mode, fin_mode);
      }
    }
  } else {
    dim3 cgrid((N_PAIRS + 63) / 64, K_OFFSETS);
    conv_atomic_kernel<<<cgrid, 256, 0, stream>>>(xb, WT0, in_map, out_map, out);
    mid_kernel<<<(N_POINTS * C / 4 + 255) / 256, 256, 0, stream>>>(features, b1, out, x1b);
    conv_atomic_kernel<<<cgrid, 256, 0, stream>>>(x1b, WT1, in_map, out_map, out);
  }
}

// Round 5
// 727.118 us; speedup vs baseline: 1.6779x; 1.3975x over previous
//
#include <hip/hip_runtime.h>

#define N_POINTS 100000
#define N_PAIRS  50000
#define K_OFFSETS 27
#define C 128
#define WPAD 136   // 128 + 8 bf16 pad; LDS row stride 272B
#define CAP 48     // CSR bucket capacity; Poisson(13.5), P(>=48) ~ 3e-12 per point

typedef __attribute__((ext_vector_type(8))) short short8;
typedef __attribute__((ext_vector_type(4))) float floatx4;

__device__ inline unsigned short f2bf(float f) {
  unsigned int u = __float_as_uint(f);
  return (unsigned short)((u + 0x7FFFu + ((u >> 16) & 1u)) >> 16);  // RNE
}
__device__ inline float bf2f(unsigned int lo16) {
  return __uint_as_float(lo16 << 16);
}

// WT[k][d*C + c] = bf16(W[k][c][d])  -- natural order for BOTH layers
__global__ __launch_bounds__(256) void prep_w_kernel(
    const float* __restrict__ W0, const float* __restrict__ W1,
    unsigned short* __restrict__ WT0, unsigned short* __restrict__ WT1) {
  int i = blockIdx.x * 256 + threadIdx.x;
  const int per = K_OFFSETS * C * C;
  if (i >= 2 * per) return;
  const float* W = (i < per) ? W0 : W1;
  unsigned short* WT = (i < per) ? WT0 : WT1;
  int r = (i < per) ? i : i - per;
  int k = r / (C * C);
  int q = r % (C * C);
  int d = q / C;
  int c = q % C;
  WT[k * C * C + d * C + c] = f2bf(W[k * C * C + c * C + d]);
}

// xb = bf16(features); out = broadcast(b0) only on the fallback path
__global__ __launch_bounds__(256) void prep_x_kernel(
    const float* __restrict__ features, const float* __restrict__ b0,
    unsigned short* __restrict__ xb, float* __restrict__ out, int write_out) {
  int i = (blockIdx.x * 256 + threadIdx.x) * 4;
  if (i >= N_POINTS * C) return;
  float4 f = *(const float4*)&features[i];
  ushort4 u;
  u.x = f2bf(f.x); u.y = f2bf(f.y); u.z = f2bf(f.z); u.w = f2bf(f.w);
  *(ushort4*)&xb[i] = u;
  if (write_out) {
    float4 b = *(const float4*)&b0[i & 127];
    *(float4*)&out[i] = b;
  }
}

__global__ __launch_bounds__(256) void zero_counts_kernel(int* __restrict__ counts) {
  int i = blockIdx.x * 256 + threadIdx.x;
  if (i < N_POINTS) counts[i] = 0;
}

// bucketed CSR of out_map: entry = (k<<16) | p  (p < 50000 < 2^16)
__global__ __launch_bounds__(256) void build_csr_kernel(
    const int* __restrict__ out_map, int* __restrict__ counts, int* __restrict__ idxbuf) {
  int flat = blockIdx.x * 256 + threadIdx.x;
  if (flat >= K_OFFSETS * N_PAIRS) return;
  int o = out_map[flat];
  int k = flat / N_PAIRS;
  int p = flat - k * N_PAIRS;
  int pos = atomicAdd(&counts[o], 1);
  if (pos < CAP) idxbuf[o * CAP + pos] = (k << 16) | p;
}

// Phase A: msg[(k-k0)*P + p][slot j] = bf16((x[in_map[k,p]] @ W[k])[chan(j)])
// chan(j) = (j&7)*16 + (j>>3); slot order comes free from the MFMA D regs.
__global__ __launch_bounds__(256, 4) void conv_msg_kernel(
    const unsigned short* __restrict__ xb, const unsigned short* __restrict__ wbt,
    const int* __restrict__ in_map, unsigned short* __restrict__ msg, int k0) {
  __shared__ unsigned short Wlds[C * WPAD];

  const int k = k0 + blockIdx.y;
  const int pairBase = blockIdx.x * 64;
  const int tid = threadIdx.x;

  const unsigned short* wk = wbt + k * C * C;
#pragma unroll
  for (int it = 0; it < 8; ++it) {
    int t = tid + it * 256;
    int row = t >> 4;
    int col = (t & 15) << 3;
    *(uint4*)&Wlds[row * WPAD + col] = *(const uint4*)&wk[row * C + col];
  }
  __syncthreads();

  const int wave = tid >> 6;
  const int lane = tid & 63;
  const int l15 = lane & 15;
  const int kg = lane >> 4;
  const int pair0 = pairBase + wave * 16;

  const int prA = pair0 + l15;
  const int inIdx = (prA < N_PAIRS) ? in_map[k * N_PAIRS + prA] : 0;
  const unsigned short* arow = xb + (size_t)inIdx * C + kg * 8;

  floatx4 acc[8];
#pragma unroll
  for (int nt = 0; nt < 8; ++nt) acc[nt] = (floatx4){0.f, 0.f, 0.f, 0.f};

#pragma unroll
  for (int kk = 0; kk < 4; ++kk) {
    short8 a = *(const short8*)(arow + kk * 32);
    const unsigned short* bbase = &Wlds[l15 * WPAD + kk * 32 + kg * 8];
#pragma unroll
    for (int nt = 0; nt < 8; ++nt) {
      short8 b = *(const short8*)(bbase + nt * 16 * WPAD);
      acc[nt] = __builtin_amdgcn_mfma_f32_16x16x32_bf16(a, b, acc[nt], 0, 0, 0);
    }
  }

  // store slot j = l15*8 + nt -> lane's 8 values contiguous (uint4, coalesced)
#pragma unroll
  for (int i = 0; i < 4; ++i) {
    int pr = pair0 + kg * 4 + i;
    if (pr < N_PAIRS) {
      unsigned short* row = msg + (size_t)(blockIdx.y * N_PAIRS + pr) * C;
      uint4 v;
      v.x = (unsigned int)f2bf(acc[0][i]) | ((unsigned int)f2bf(acc[1][i]) << 16);
      v.y = (unsigned int)f2bf(acc[2][i]) | ((unsigned int)f2bf(acc[3][i]) << 16);
      v.z = (unsigned int)f2bf(acc[4][i]) | ((unsigned int)f2bf(acc[5][i]) << 16);
      v.w = (unsigned int)f2bf(acc[6][i]) | ((unsigned int)f2bf(acc[7][i]) << 16);
      *(uint4*)(row + l15 * 8) = v;
    }
  }
}

// Phase B: one wave per output point; lane owns channels c0, c0+16 (slots 2*lane, 2*lane+1).
// v2: idx list preloaded with ONE coalesced load, chunk-filtered and wave-compacted
// via ballot into LDS, then an unconditional unroll-4 loop of independent msg loads
// (MLP >= 4, no per-iteration dependent idx load, no divergent branch).
// Grid is exactly N_POINTS/4 blocks (100000 % 4 == 0): no early-return, barrier safe.
// init_mode: 0 = resume from out, 1 = bias (layer1 first), 2 = bias + residual (layer2 first)
// fin_mode:  0 = write out (fp32), 1 = relu -> x1b (bf16, layer1 last)
__global__ __launch_bounds__(256) void gather_kernel(
    const unsigned short* __restrict__ msg, const int* __restrict__ counts,
    const int* __restrict__ idxbuf, const float* __restrict__ bias,
    const float* __restrict__ features, float* __restrict__ out,
    unsigned short* __restrict__ x1b,
    int k0, int G, int init_mode, int fin_mode) {
  __shared__ int elds[4][64];
  const int wave = threadIdx.x >> 6;
  const int lane = threadIdx.x & 63;
  const int oi = blockIdx.x * 4 + wave;

  const int c0 = ((2 * lane) & 7) * 16 + (lane >> 2);
  const int c1 = c0 + 16;
  const size_t base = (size_t)oi * C;

  float a0, a1;
  if (init_mode == 1)      { a0 = bias[c0]; a1 = bias[c1]; }
  else if (init_mode == 2) { a0 = bias[c0] + features[base + c0];
                             a1 = bias[c1] + features[base + c1]; }
  else                     { a0 = out[base + c0]; a1 = out[base + c1]; }

  int cnt = counts[oi]; if (cnt > CAP) cnt = CAP;

  // one coalesced preload of this point's entry list (CAP=48 <= 64 lanes)
  int e_mine = (lane < cnt) ? idxbuf[oi * CAP + lane] : 0;
  bool ok = false;
  if (lane < cnt) {
    unsigned int rel = ((unsigned int)e_mine >> 16) - (unsigned int)k0;
    ok = rel < (unsigned int)G;
  }
  unsigned long long mask = __ballot(ok);
  int cnt2 = __popcll(mask);
  if (ok) {
    int pos = __popcll(mask & ((1ull << lane) - 1ull));
    // store pre-resolved chunk-relative flat pair index (rel*N_PAIRS + p)
    unsigned int rel = ((unsigned int)e_mine >> 16) - (unsigned int)k0;
    elds[wave][pos] = (int)(rel * N_PAIRS + ((unsigned int)e_mine & 0xffffu));
  }
  __syncthreads();

  const unsigned short* mbase = msg + 2 * lane;
  int t = 0;
  for (; t + 4 <= cnt2; t += 4) {
    int f0 = elds[wave][t];
    int f1 = elds[wave][t + 1];
    int f2 = elds[wave][t + 2];
    int f3 = elds[wave][t + 3];
    unsigned int v0 = *(const unsigned int*)(mbase + (size_t)f0 * C);
    unsigned int v1 = *(const unsigned int*)(mbase + (size_t)f1 * C);
    unsigned int v2 = *(const unsigned int*)(mbase + (size_t)f2 * C);
    unsigned int v3 = *(const unsigned int*)(mbase + (size_t)f3 * C);
    a0 += bf2f(v0 & 0xffffu) + bf2f(v1 & 0xffffu) + bf2f(v2 & 0xffffu) + bf2f(v3 & 0xffffu);
    a1 += bf2f(v0 >> 16) + bf2f(v1 >> 16) + bf2f(v2 >> 16) + bf2f(v3 >> 16);
  }
  for (; t < cnt2; ++t) {
    int f0 = elds[wave][t];
    unsigned int v = *(const unsigned int*)(mbase + (size_t)f0 * C);
    a0 += bf2f(v & 0xffffu);
    a1 += bf2f(v >> 16);
  }

  if (fin_mode == 1) {
    x1b[base + c0] = f2bf(fmaxf(a0, 0.f));
    x1b[base + c1] = f2bf(fmaxf(a1, 0.f));
  } else {
    out[base + c0] = a0;
    out[base + c1] = a1;
  }
}

// ---------------- fallback (round-1 atomic path, <53 MB ws, natural WT1) ----------------
__global__ __launch_bounds__(256) void mid_kernel(
    const float* __restrict__ features, const float* __restrict__ b1,
    float* __restrict__ out, unsigned short* __restrict__ x1b) {
  int i = (blockIdx.x * 256 + threadIdx.x) * 4;
  if (i >= N_POINTS * C) return;
  float4 y = *(const float4*)&out[i];
  ushort4 u;
  u.x = f2bf(fmaxf(y.x, 0.f));
  u.y = f2bf(fmaxf(y.y, 0.f));
  u.z = f2bf(fmaxf(y.z, 0.f));
  u.w = f2bf(fmaxf(y.w, 0.f));
  *(ushort4*)&x1b[i] = u;
  float4 f = *(const float4*)&features[i];
  float4 b = *(const float4*)&b1[i & 127];
  float4 o;
  o.x = f.x + b.x; o.y = f.y + b.y; o.z = f.z + b.z; o.w = f.w + b.w;
  *(float4*)&out[i] = o;
}

__global__ __launch_bounds__(256, 4) void conv_atomic_kernel(
    const unsigned short* __restrict__ xb, const unsigned short* __restrict__ wbt,
    const int* __restrict__ in_map, const int* __restrict__ out_map,
    float* __restrict__ out) {
  __shared__ unsigned short Wlds[C * WPAD];
  const int k = blockIdx.y;
  const int pairBase = blockIdx.x * 64;
  const int tid = threadIdx.x;
  const unsigned short* wk = wbt + k * C * C;
#pragma unroll
  for (int it = 0; it < 8; ++it) {
    int t = tid + it * 256;
    int row = t >> 4;
    int col = (t & 15) << 3;
    *(uint4*)&Wlds[row * WPAD + col] = *(const uint4*)&wk[row * C + col];
  }
  __syncthreads();
  const int wave = tid >> 6;
  const int lane = tid & 63;
  const int l15 = lane & 15;
  const int kg = lane >> 4;
  const int pair0 = pairBase + wave * 16;
  const int prA = pair0 + l15;
  const int inIdx = (prA < N_PAIRS) ? in_map[k * N_PAIRS + prA] : 0;
  const unsigned short* arow = xb + (size_t)inIdx * C + kg * 8;
  floatx4 acc[8];
#pragma unroll
  for (int nt = 0; nt < 8; ++nt) acc[nt] = (floatx4){0.f, 0.f, 0.f, 0.f};
#pragma unroll
  for (int kk = 0; kk < 4; ++kk) {
    short8 a = *(const short8*)(arow + kk * 32);
    const unsigned short* bbase = &Wlds[l15 * WPAD + kk * 32 + kg * 8];
#pragma unroll
    for (int nt = 0; nt < 8; ++nt) {
      short8 b = *(const short8*)(bbase + nt * 16 * WPAD);
      acc[nt] = __builtin_amdgcn_mfma_f32_16x16x32_bf16(a, b, acc[nt], 0, 0, 0);
    }
  }
#pragma unroll
  for (int i = 0; i < 4; ++i) {
    int pr = pair0 + kg * 4 + i;
    if (pr < N_PAIRS) {
      int oi = out_map[k * N_PAIRS + pr];
      float* orow = out + (size_t)oi * C + l15;
#pragma unroll
      for (int nt = 0; nt < 8; ++nt) atomicAdd(orow + nt * 16, acc[nt][i]);
    }
  }
}

extern "C" void kernel_launch(void* const* d_in, const int* in_sizes, int n_in,
                              void* d_out, int out_size, void* d_ws, size_t ws_size,
                              hipStream_t stream) {
  const float* features = (const float*)d_in[0];
  const int* in_map     = (const int*)d_in[1];
  const int* out_map    = (const int*)d_in[2];
  const float* W0       = (const float*)d_in[3];
  const float* b0       = (const float*)d_in[4];
  const float* W1       = (const float*)d_in[5];
  const float* b1       = (const float*)d_in[6];
  float* out = (float*)d_out;

  char* ws = (char*)d_ws;
  unsigned short* xb  = (unsigned short*)(ws);                  // 25,600,000
  unsigned short* x1b = (unsigned short*)(ws + 25600000);       // 25,600,000
  unsigned short* WT0 = (unsigned short*)(ws + 51200000);       //    884,736
  unsigned short* WT1 = (unsigned short*)(ws + 52084736);       //    884,736
  int* counts         = (int*)(ws + 52969472);                  //    400,384
  int* idxbuf         = (int*)(ws + 53369856);                  // 19,200,000 (100000*CAP*4)
  unsigned short* msg = (unsigned short*)(ws + 72569856);       // G * 12,800,000

  const long long MSG_K_BYTES = (long long)N_PAIRS * C * 2;     // 12.8 MB per offset
  long long avail = (long long)ws_size - 72569856LL;
  int G = 0;
  if (avail >= MSG_K_BYTES) {
    long long g = avail / MSG_K_BYTES;
    G = (int)(g > K_OFFSETS ? K_OFFSETS : g);
  }

  prep_w_kernel<<<(2 * K_OFFSETS * C * C + 255) / 256, 256, 0, stream>>>(W0, W1, WT0, WT1);
  prep_x_kernel<<<(N_POINTS * C / 4 + 255) / 256, 256, 0, stream>>>(
      features, b0, xb, out, (G > 0) ? 0 : 1);

  if (G > 0) {
    zero_counts_kernel<<<(N_POINTS + 255) / 256, 256, 0, stream>>>(counts);
    build_csr_kernel<<<(K_OFFSETS * N_PAIRS + 255) / 256, 256, 0, stream>>>(out_map, counts, idxbuf);

    const int nchunks = (K_OFFSETS + G - 1) / G;
    for (int layer = 0; layer < 2; ++layer) {
      const unsigned short* xin = layer ? x1b : xb;
      const unsigned short* wt  = layer ? WT1 : WT0;
      const float* bias         = layer ? b1  : b0;
      for (int c = 0; c < nchunks; ++c) {
        int k0 = c * G;
        int Gc = K_OFFSETS - k0 < G ? K_OFFSETS - k0 : G;
        dim3 cgrid((N_PAIRS + 63) / 64, Gc);
        conv_msg_kernel<<<cgrid, 256, 0, stream>>>(xin, wt, in_map, msg, k0);
        int init_mode = (c == 0) ? (layer ? 2 : 1) : 0;
        int fin_mode  = (layer == 0 && c == nchunks - 1) ? 1 : 0;
        gather_kernel<<<N_POINTS / 4, 256, 0, stream>>>(
            msg, counts, idxbuf, bias, features, out, x1b, k0, Gc, init_mode, fin_mode);
      }
    }
  } else {
    dim3 cgrid((N_PAIRS + 63) / 64, K_OFFSETS);
    conv_atomic_kernel<<<cgrid, 256, 0, stream>>>(xb, WT0, in_map, out_map, out);
    mid_kernel<<<(N_POINTS * C / 4 + 255) / 256, 256, 0, stream>>>(features, b1, out, x1b);
    conv_atomic_kernel<<<cgrid, 256, 0, stream>>>(x1b, WT1, in_map, out_map, out);
  }
}

// Round 6
// 721.353 us; speedup vs baseline: 1.6913x; 1.0080x over previous
//
#include <hip/hip_runtime.h>

#define N_POINTS 100000
#define N_PAIRS  50000
#define K_OFFSETS 27
#define C 128
#define WPAD 136   // 128 + 8 bf16 pad; LDS row stride 272B
#define CAP 48     // CSR bucket capacity; Poisson(13.5), P(>=48) ~ 3e-12 per point

typedef __attribute__((ext_vector_type(8))) short short8;
typedef __attribute__((ext_vector_type(4))) float floatx4;

__device__ inline unsigned short f2bf(float f) {
  unsigned int u = __float_as_uint(f);
  return (unsigned short)((u + 0x7FFFu + ((u >> 16) & 1u)) >> 16);  // RNE
}
__device__ inline float bf2f(unsigned int lo16) {
  return __uint_as_float(lo16 << 16);
}

// WT[k][d*C + c] = bf16(W[k][c][d])  -- natural order for BOTH layers
__global__ __launch_bounds__(256) void prep_w_kernel(
    const float* __restrict__ W0, const float* __restrict__ W1,
    unsigned short* __restrict__ WT0, unsigned short* __restrict__ WT1) {
  int i = blockIdx.x * 256 + threadIdx.x;
  const int per = K_OFFSETS * C * C;
  if (i >= 2 * per) return;
  const float* W = (i < per) ? W0 : W1;
  unsigned short* WT = (i < per) ? WT0 : WT1;
  int r = (i < per) ? i : i - per;
  int k = r / (C * C);
  int q = r % (C * C);
  int d = q / C;
  int c = q % C;
  WT[k * C * C + d * C + c] = f2bf(W[k * C * C + c * C + d]);
}

// xb = bf16(features); out = broadcast(b0) only on the fallback path
__global__ __launch_bounds__(256) void prep_x_kernel(
    const float* __restrict__ features, const float* __restrict__ b0,
    unsigned short* __restrict__ xb, float* __restrict__ out, int write_out) {
  int i = (blockIdx.x * 256 + threadIdx.x) * 4;
  if (i >= N_POINTS * C) return;
  float4 f = *(const float4*)&features[i];
  ushort4 u;
  u.x = f2bf(f.x); u.y = f2bf(f.y); u.z = f2bf(f.z); u.w = f2bf(f.w);
  *(ushort4*)&xb[i] = u;
  if (write_out) {
    float4 b = *(const float4*)&b0[i & 127];
    *(float4*)&out[i] = b;
  }
}

__global__ __launch_bounds__(256) void zero_counts_kernel(int* __restrict__ counts) {
  int i = blockIdx.x * 256 + threadIdx.x;
  if (i < N_POINTS) counts[i] = 0;
}

// bucketed CSR of out_map: entry = (k<<16) | p  (p < 50000 < 2^16)
// v3: 4 entries per thread, one int4 load, 4 independent atomic->store chains (MLP=4)
__global__ __launch_bounds__(256) void build_csr_kernel(
    const int* __restrict__ out_map, int* __restrict__ counts, int* __restrict__ idxbuf) {
  int base = (blockIdx.x * 256 + threadIdx.x) * 4;
  if (base >= K_OFFSETS * N_PAIRS) return;   // total 1,350,000 divisible by 4
  int4 o4 = *(const int4*)&out_map[base];
  int o[4] = {o4.x, o4.y, o4.z, o4.w};
  int pos[4];
#pragma unroll
  for (int j = 0; j < 4; ++j) pos[j] = atomicAdd(&counts[o[j]], 1);
#pragma unroll
  for (int j = 0; j < 4; ++j) {
    int flat = base + j;
    int k = flat / N_PAIRS;
    int p = flat - k * N_PAIRS;
    if (pos[j] < CAP) idxbuf[o[j] * CAP + pos[j]] = (k << 16) | p;
  }
}

// Phase A: msg[(k-k0)*P + p][slot j] = bf16((x[in_map[k,p]] @ W[k])[chan(j)])
// chan(j) = (j&7)*16 + (j>>3); slot order comes free from the MFMA D regs.
// v2: 128 pairs per block -- each wave runs 2 A-tiles against the same LDS W
// (halves W-staging per pair, 64 MFMA per wave per block).
__global__ __launch_bounds__(256, 4) void conv_msg_kernel(
    const unsigned short* __restrict__ xb, const unsigned short* __restrict__ wbt,
    const int* __restrict__ in_map, unsigned short* __restrict__ msg, int k0) {
  __shared__ unsigned short Wlds[C * WPAD];

  const int k = k0 + blockIdx.y;
  const int pairBase = blockIdx.x * 128;
  const int tid = threadIdx.x;

  const unsigned short* wk = wbt + k * C * C;
#pragma unroll
  for (int it = 0; it < 8; ++it) {
    int t = tid + it * 256;
    int row = t >> 4;
    int col = (t & 15) << 3;
    *(uint4*)&Wlds[row * WPAD + col] = *(const uint4*)&wk[row * C + col];
  }
  __syncthreads();

  const int wave = tid >> 6;
  const int lane = tid & 63;
  const int l15 = lane & 15;
  const int kg = lane >> 4;
  const int pair0 = pairBase + wave * 32;        // this wave's 32 pairs (2 tiles)

  const int prA0 = pair0 + l15;
  const int prA1 = pair0 + 16 + l15;
  const int inIdx0 = (prA0 < N_PAIRS) ? in_map[k * N_PAIRS + prA0] : 0;
  const int inIdx1 = (prA1 < N_PAIRS) ? in_map[k * N_PAIRS + prA1] : 0;
  const unsigned short* arow0 = xb + (size_t)inIdx0 * C + kg * 8;
  const unsigned short* arow1 = xb + (size_t)inIdx1 * C + kg * 8;

  floatx4 acc0[8], acc1[8];
#pragma unroll
  for (int nt = 0; nt < 8; ++nt) {
    acc0[nt] = (floatx4){0.f, 0.f, 0.f, 0.f};
    acc1[nt] = (floatx4){0.f, 0.f, 0.f, 0.f};
  }

#pragma unroll
  for (int kk = 0; kk < 4; ++kk) {
    short8 a0 = *(const short8*)(arow0 + kk * 32);
    short8 a1 = *(const short8*)(arow1 + kk * 32);
    const unsigned short* bbase = &Wlds[l15 * WPAD + kk * 32 + kg * 8];
#pragma unroll
    for (int nt = 0; nt < 8; ++nt) {
      short8 b = *(const short8*)(bbase + nt * 16 * WPAD);
      acc0[nt] = __builtin_amdgcn_mfma_f32_16x16x32_bf16(a0, b, acc0[nt], 0, 0, 0);
      acc1[nt] = __builtin_amdgcn_mfma_f32_16x16x32_bf16(a1, b, acc1[nt], 0, 0, 0);
    }
  }

  // store slot j = l15*8 + nt -> lane's 8 values contiguous (uint4, coalesced)
#pragma unroll
  for (int i = 0; i < 4; ++i) {
    int pr0 = pair0 + kg * 4 + i;
    if (pr0 < N_PAIRS) {
      unsigned short* row = msg + (size_t)(blockIdx.y * N_PAIRS + pr0) * C;
      uint4 v;
      v.x = (unsigned int)f2bf(acc0[0][i]) | ((unsigned int)f2bf(acc0[1][i]) << 16);
      v.y = (unsigned int)f2bf(acc0[2][i]) | ((unsigned int)f2bf(acc0[3][i]) << 16);
      v.z = (unsigned int)f2bf(acc0[4][i]) | ((unsigned int)f2bf(acc0[5][i]) << 16);
      v.w = (unsigned int)f2bf(acc0[6][i]) | ((unsigned int)f2bf(acc0[7][i]) << 16);
      *(uint4*)(row + l15 * 8) = v;
    }
    int pr1 = pair0 + 16 + kg * 4 + i;
    if (pr1 < N_PAIRS) {
      unsigned short* row = msg + (size_t)(blockIdx.y * N_PAIRS + pr1) * C;
      uint4 v;
      v.x = (unsigned int)f2bf(acc1[0][i]) | ((unsigned int)f2bf(acc1[1][i]) << 16);
      v.y = (unsigned int)f2bf(acc1[2][i]) | ((unsigned int)f2bf(acc1[3][i]) << 16);
      v.z = (unsigned int)f2bf(acc1[4][i]) | ((unsigned int)f2bf(acc1[5][i]) << 16);
      v.w = (unsigned int)f2bf(acc1[6][i]) | ((unsigned int)f2bf(acc1[7][i]) << 16);
      *(uint4*)(row + l15 * 8) = v;
    }
  }
}

// Phase B: one wave per output point; lane owns channels c0, c0+16 (slots 2*lane, 2*lane+1).
// idx list preloaded with ONE coalesced load, chunk-filtered and wave-compacted
// via ballot into LDS, then an unconditional unroll-4 loop of independent msg loads.
// Grid is exactly N_POINTS/4 blocks (100000 % 4 == 0): no early-return, barrier safe.
// init_mode: 0 = resume from out, 1 = bias (layer1 first), 2 = bias + residual (layer2 first)
// fin_mode:  0 = write out (fp32), 1 = relu -> x1b (bf16, layer1 last)
__global__ __launch_bounds__(256) void gather_kernel(
    const unsigned short* __restrict__ msg, const int* __restrict__ counts,
    const int* __restrict__ idxbuf, const float* __restrict__ bias,
    const float* __restrict__ features, float* __restrict__ out,
    unsigned short* __restrict__ x1b,
    int k0, int G, int init_mode, int fin_mode) {
  __shared__ int elds[4][64];
  const int wave = threadIdx.x >> 6;
  const int lane = threadIdx.x & 63;
  const int oi = blockIdx.x * 4 + wave;

  const int c0 = ((2 * lane) & 7) * 16 + (lane >> 2);
  const int c1 = c0 + 16;
  const size_t base = (size_t)oi * C;

  float a0, a1;
  if (init_mode == 1)      { a0 = bias[c0]; a1 = bias[c1]; }
  else if (init_mode == 2) { a0 = bias[c0] + features[base + c0];
                             a1 = bias[c1] + features[base + c1]; }
  else                     { a0 = out[base + c0]; a1 = out[base + c1]; }

  int cnt = counts[oi]; if (cnt > CAP) cnt = CAP;

  // one coalesced preload of this point's entry list (CAP=48 <= 64 lanes)
  int e_mine = (lane < cnt) ? idxbuf[oi * CAP + lane] : 0;
  bool ok = false;
  if (lane < cnt) {
    unsigned int rel = ((unsigned int)e_mine >> 16) - (unsigned int)k0;
    ok = rel < (unsigned int)G;
  }
  unsigned long long mask = __ballot(ok);
  int cnt2 = __popcll(mask);
  if (ok) {
    int pos = __popcll(mask & ((1ull << lane) - 1ull));
    unsigned int rel = ((unsigned int)e_mine >> 16) - (unsigned int)k0;
    elds[wave][pos] = (int)(rel * N_PAIRS + ((unsigned int)e_mine & 0xffffu));
  }
  __syncthreads();

  const unsigned short* mbase = msg + 2 * lane;
  int t = 0;
  for (; t + 4 <= cnt2; t += 4) {
    int f0 = elds[wave][t];
    int f1 = elds[wave][t + 1];
    int f2 = elds[wave][t + 2];
    int f3 = elds[wave][t + 3];
    unsigned int v0 = *(const unsigned int*)(mbase + (size_t)f0 * C);
    unsigned int v1 = *(const unsigned int*)(mbase + (size_t)f1 * C);
    unsigned int v2 = *(const unsigned int*)(mbase + (size_t)f2 * C);
    unsigned int v3 = *(const unsigned int*)(mbase + (size_t)f3 * C);
    a0 += bf2f(v0 & 0xffffu) + bf2f(v1 & 0xffffu) + bf2f(v2 & 0xffffu) + bf2f(v3 & 0xffffu);
    a1 += bf2f(v0 >> 16) + bf2f(v1 >> 16) + bf2f(v2 >> 16) + bf2f(v3 >> 16);
  }
  for (; t < cnt2; ++t) {
    int f0 = elds[wave][t];
    unsigned int v = *(const unsigned int*)(mbase + (size_t)f0 * C);
    a0 += bf2f(v & 0xffffu);
    a1 += bf2f(v >> 16);
  }

  if (fin_mode == 1) {
    x1b[base + c0] = f2bf(fmaxf(a0, 0.f));
    x1b[base + c1] = f2bf(fmaxf(a1, 0.f));
  } else {
    out[base + c0] = a0;
    out[base + c1] = a1;
  }
}

// ---------------- fallback (round-1 atomic path, <53 MB ws, natural WT1) ----------------
__global__ __launch_bounds__(256) void mid_kernel(
    const float* __restrict__ features, const float* __restrict__ b1,
    float* __restrict__ out, unsigned short* __restrict__ x1b) {
  int i = (blockIdx.x * 256 + threadIdx.x) * 4;
  if (i >= N_POINTS * C) return;
  float4 y = *(const float4*)&out[i];
  ushort4 u;
  u.x = f2bf(fmaxf(y.x, 0.f));
  u.y = f2bf(fmaxf(y.y, 0.f));
  u.z = f2bf(fmaxf(y.z, 0.f));
  u.w = f2bf(fmaxf(y.w, 0.f));
  *(ushort4*)&x1b[i] = u;
  float4 f = *(const float4*)&features[i];
  float4 b = *(const float4*)&b1[i & 127];
  float4 o;
  o.x = f.x + b.x; o.y = f.y + b.y; o.z = f.z + b.z; o.w = f.w + b.w;
  *(float4*)&out[i] = o;
}

__global__ __launch_bounds__(256, 4) void conv_atomic_kernel(
    const unsigned short* __restrict__ xb, const unsigned short* __restrict__ wbt,
    const int* __restrict__ in_map, const int* __restrict__ out_map,
    float* __restrict__ out) {
  __shared__ unsigned short Wlds[C * WPAD];
  const int k = blockIdx.y;
  const int pairBase = blockIdx.x * 64;
  const int tid = threadIdx.x;
  const unsigned short* wk = wbt + k * C * C;
#pragma unroll
  for (int it = 0; it < 8; ++it) {
    int t = tid + it * 256;
    int row = t >> 4;
    int col = (t & 15) << 3;
    *(uint4*)&Wlds[row * WPAD + col] = *(const uint4*)&wk[row * C + col];
  }
  __syncthreads();
  const int wave = tid >> 6;
  const int lane = tid & 63;
  const int l15 = lane & 15;
  const int kg = lane >> 4;
  const int pair0 = pairBase + wave * 16;
  const int prA = pair0 + l15;
  const int inIdx = (prA < N_PAIRS) ? in_map[k * N_PAIRS + prA] : 0;
  const unsigned short* arow = xb + (size_t)inIdx * C + kg * 8;
  floatx4 acc[8];
#pragma unroll
  for (int nt = 0; nt < 8; ++nt) acc[nt] = (floatx4){0.f, 0.f, 0.f, 0.f};
#pragma unroll
  for (int kk = 0; kk < 4; ++kk) {
    short8 a = *(const short8*)(arow + kk * 32);
    const unsigned short* bbase = &Wlds[l15 * WPAD + kk * 32 + kg * 8];
#pragma unroll
    for (int nt = 0; nt < 8; ++nt) {
      short8 b = *(const short8*)(bbase + nt * 16 * WPAD);
      acc[nt] = __builtin_amdgcn_mfma_f32_16x16x32_bf16(a, b, acc[nt], 0, 0, 0);
    }
  }
#pragma unroll
  for (int i = 0; i < 4; ++i) {
    int pr = pair0 + kg * 4 + i;
    if (pr < N_PAIRS) {
      int oi = out_map[k * N_PAIRS + pr];
      float* orow = out + (size_t)oi * C + l15;
#pragma unroll
      for (int nt = 0; nt < 8; ++nt) atomicAdd(orow + nt * 16, acc[nt][i]);
    }
  }
}

extern "C" void kernel_launch(void* const* d_in, const int* in_sizes, int n_in,
                              void* d_out, int out_size, void* d_ws, size_t ws_size,
                              hipStream_t stream) {
  const float* features = (const float*)d_in[0];
  const int* in_map     = (const int*)d_in[1];
  const int* out_map    = (const int*)d_in[2];
  const float* W0       = (const float*)d_in[3];
  const float* b0       = (const float*)d_in[4];
  const float* W1       = (const float*)d_in[5];
  const float* b1       = (const float*)d_in[6];
  float* out = (float*)d_out;

  char* ws = (char*)d_ws;
  unsigned short* xb  = (unsigned short*)(ws);                  // 25,600,000
  unsigned short* x1b = (unsigned short*)(ws + 25600000);       // 25,600,000
  unsigned short* WT0 = (unsigned short*)(ws + 51200000);       //    884,736
  unsigned short* WT1 = (unsigned short*)(ws + 52084736);       //    884,736
  int* counts         = (int*)(ws + 52969472);                  //    400,384
  int* idxbuf         = (int*)(ws + 53369856);                  // 19,200,000 (100000*CAP*4)
  unsigned short* msg = (unsigned short*)(ws + 72569856);       // G * 12,800,000

  const long long MSG_K_BYTES = (long long)N_PAIRS * C * 2;     // 12.8 MB per offset
  long long avail = (long long)ws_size - 72569856LL;
  int G = 0;
  if (avail >= MSG_K_BYTES) {
    long long g = avail / MSG_K_BYTES;
    G = (int)(g > K_OFFSETS ? K_OFFSETS : g);
  }

  prep_w_kernel<<<(2 * K_OFFSETS * C * C + 255) / 256, 256, 0, stream>>>(W0, W1, WT0, WT1);
  prep_x_kernel<<<(N_POINTS * C / 4 + 255) / 256, 256, 0, stream>>>(
      features, b0, xb, out, (G > 0) ? 0 : 1);

  if (G > 0) {
    zero_counts_kernel<<<(N_POINTS + 255) / 256, 256, 0, stream>>>(counts);
    build_csr_kernel<<<(K_OFFSETS * N_PAIRS / 4 + 255) / 256, 256, 0, stream>>>(out_map, counts, idxbuf);

    const int nchunks = (K_OFFSETS + G - 1) / G;
    for (int layer = 0; layer < 2; ++layer) {
      const unsigned short* xin = layer ? x1b : xb;
      const unsigned short* wt  = layer ? WT1 : WT0;
      const float* bias         = layer ? b1  : b0;
      for (int c = 0; c < nchunks; ++c) {
        int k0 = c * G;
        int Gc = K_OFFSETS - k0 < G ? K_OFFSETS - k0 : G;
        dim3 cgrid((N_PAIRS + 127) / 128, Gc);
        conv_msg_kernel<<<cgrid, 256, 0, stream>>>(xin, wt, in_map, msg, k0);
        int init_mode = (c == 0) ? (layer ? 2 : 1) : 0;
        int fin_mode  = (layer == 0 && c == nchunks - 1) ? 1 : 0;
        gather_kernel<<<N_POINTS / 4, 256, 0, stream>>>(
            msg, counts, idxbuf, bias, features, out, x1b, k0, Gc, init_mode, fin_mode);
      }
    }
  } else {
    dim3 cgrid((N_PAIRS + 63) / 64, K_OFFSETS);
    conv_atomic_kernel<<<cgrid, 256, 0, stream>>>(xb, WT0, in_map, out_map, out);
    mid_kernel<<<(N_POINTS * C / 4 + 255) / 256, 256, 0, stream>>>(features, b1, out, x1b);
    conv_atomic_kernel<<<cgrid, 256, 0, stream>>>(x1b, WT1, in_map, out_map, out);
  }
}